// Round 3
// baseline (956.360 us; speedup 1.0000x reference)
//
#include <hip/hip_runtime.h>

#define C 128
#define DD 256
#define NOUT 2
#define ALPHA 0.1f
#define SLOPE 0.01f
#define ZSTR 132   // padded LDS row stride (floats)
#define NCH 8      // channel chunks (16 floats each) for L2-resident gather

// ---------------- graph preprocessing ----------------

__global__ void count_kernel(const int* __restrict__ col, int* __restrict__ cnt, int E) {
    int e = blockIdx.x * 256 + threadIdx.x;
    if (e < E) atomicAdd(&cnt[col[e]], 1);
}

__global__ void dinv_kernel(const int* __restrict__ cnt, float* __restrict__ dinv, int n) {
    int i = blockIdx.x * 256 + threadIdx.x;
    if (i < n) dinv[i] = rsqrtf((float)(cnt[i] + 1));   // +1 self-loop; always > 0
}

// single-block exclusive scan: 1024 threads, 4 elems/thread, shuffle-based
__global__ __launch_bounds__(1024) void scan_kernel(const int* __restrict__ cnt,
                                                    int* __restrict__ offs, int n) {
    __shared__ int wsum[16];
    __shared__ int chunk_carry;
    int t = threadIdx.x;
    int lane = t & 63, wv = t >> 6;
    if (t == 0) chunk_carry = 0;
    __syncthreads();
    for (int base = 0; base < n; base += 4096) {
        int idx = base + t * 4;
        int v0 = (idx + 0 < n) ? cnt[idx + 0] : 0;
        int v1 = (idx + 1 < n) ? cnt[idx + 1] : 0;
        int v2 = (idx + 2 < n) ? cnt[idx + 2] : 0;
        int v3 = (idx + 3 < n) ? cnt[idx + 3] : 0;
        int s0 = v0, s1 = s0 + v1, s2 = s1 + v2, s3 = s2 + v3;
        int tot = s3;
        int sc = tot;
        #pragma unroll
        for (int d = 1; d < 64; d <<= 1) {
            int u = __shfl_up(sc, d);
            if (lane >= d) sc += u;
        }
        if (lane == 63) wsum[wv] = sc;
        __syncthreads();
        int woff = 0;
        #pragma unroll
        for (int j = 0; j < 16; ++j) woff += (j < wv) ? wsum[j] : 0;
        int excl = chunk_carry + woff + (sc - tot);
        if (idx + 0 < n) offs[idx + 0] = excl;
        if (idx + 1 < n) offs[idx + 1] = excl + s0;
        if (idx + 2 < n) offs[idx + 2] = excl + s1;
        if (idx + 3 < n) offs[idx + 3] = excl + s2;
        __syncthreads();
        if (t == 1023) chunk_carry = excl + s3;
        __syncthreads();
    }
    if (t == 0) offs[n] = chunk_carry;
}

__global__ void copy_kernel(const int* __restrict__ src, int* __restrict__ dst, int n) {
    int i = blockIdx.x * 256 + threadIdx.x;
    if (i < n) dst[i] = src[i];
}

// packed edge metadata: {src, float-bits of norm}
__global__ void fill_kernel(const int* __restrict__ row, const int* __restrict__ col,
                            const float* __restrict__ dinv, int* __restrict__ cursor,
                            int2* __restrict__ csr, int E) {
    int e = blockIdx.x * 256 + threadIdx.x;
    if (e >= E) return;
    int r = row[e], c = col[e];
    int pos = atomicAdd(&cursor[c], 1);
    int2 m;
    m.x = r;
    m.y = __float_as_int(dinv[r] * dinv[c]);
    csr[pos] = m;
}

// node-major -> chunk-major: xb[ch][i][16]
__global__ __launch_bounds__(256) void transpose_kernel(const float* __restrict__ x,
                                                        float* __restrict__ xb, int n) {
    int g = blockIdx.x * 256 + threadIdx.x;
    if (g >= n * 32) return;
    int i = g >> 5, c4 = g & 31;
    float4 v = ((const float4*)x)[g];
    ((float4*)xb)[(size_t)(c4 >> 2) * (n * 4) + (size_t)i * 4 + (c4 & 3)] = v;
}

// ---------------- chunked aggregation: one wave per node, 16 edges in flight ----------------
// grid = (ceil(n/4), NCH); all resident blocks share one L2-resident 3.2 MB chunk
__global__ __launch_bounds__(256) void agg_kernel(
    const float* __restrict__ xb, const int* __restrict__ offs,
    const int2* __restrict__ csr, const float* __restrict__ dinv,
    float* __restrict__ hb, int n)
{
    int i = blockIdx.x * 4 + (threadIdx.x >> 6);
    if (i >= n) return;
    int lane = threadIdx.x & 63;
    int f4 = lane & 3;          // float4 slot within 16-float chunk
    int eslot = lane >> 2;      // edge slot 0..15
    const float4* x4 = (const float4*)xb;
    size_t cbase = (size_t)blockIdx.y * (n * 4);
    int beg = offs[i], end = offs[i + 1];
    float4 acc = {0.f, 0.f, 0.f, 0.f};
    for (int k = beg + eslot; k < end; k += 16) {
        int2 m = csr[k];
        float w = __int_as_float(m.y);
        float4 v = x4[cbase + (size_t)m.x * 4 + f4];
        acc.x += w * v.x; acc.y += w * v.y; acc.z += w * v.z; acc.w += w * v.w;
    }
    #pragma unroll
    for (int ms = 4; ms <= 32; ms <<= 1) {
        acc.x += __shfl_xor(acc.x, ms);
        acc.y += __shfl_xor(acc.y, ms);
        acc.z += __shfl_xor(acc.z, ms);
        acc.w += __shfl_xor(acc.w, ms);
    }
    if (eslot == 0) {
        float di = dinv[i];
        float w0 = di * di;
        float4 s = x4[cbase + (size_t)i * 4 + f4];
        acc.x += w0 * s.x; acc.y += w0 * s.y; acc.z += w0 * s.z; acc.w += w0 * s.w;
        ((float4*)hb)[cbase + (size_t)i * 4 + f4] = acc;
    }
}

// chunk-major float4 index for (node i, float4-col c4)
__device__ __forceinline__ size_t a4(int i, int c4, int n) {
    return (size_t)(c4 >> 2) * (n * 4) + (size_t)i * 4 + (c4 & 3);
}

// ---------------- layer GEMM: xn = leaky(((1-a)h + a*x0) @ W), in-place (xn == h ok)
// h/xn chunk-major, x0 node-major
__global__ __launch_bounds__(256) void layer_gemm(
    const float* __restrict__ h, const float* __restrict__ x0,
    const float* __restrict__ W, float* __restrict__ xn, int n)
{
    __shared__ float z[64 * ZSTR];
    int i0 = blockIdx.x * 64;
    int t = threadIdx.x;
    for (int p = t; p < 64 * 32; p += 256) {
        int r = p >> 5, c4 = p & 31;
        float4 zv = {0.f, 0.f, 0.f, 0.f};
        if (i0 + r < n) {
            float4 hv = ((const float4*)h)[a4(i0 + r, c4, n)];
            float4 xv = ((const float4*)x0)[(size_t)(i0 + r) * 32 + c4];
            zv.x = (1.f - ALPHA) * hv.x + ALPHA * xv.x;
            zv.y = (1.f - ALPHA) * hv.y + ALPHA * xv.y;
            zv.z = (1.f - ALPHA) * hv.z + ALPHA * xv.z;
            zv.w = (1.f - ALPHA) * hv.w + ALPHA * xv.w;
        }
        *(float4*)&z[r * ZSTR + c4 * 4] = zv;
    }
    __syncthreads();

    int cl = t & 31;
    int ng = t >> 5;
    float4 acc[8] = {};
    const float4* W4 = (const float4*)W;
    float4 w0 = W4[0 * 32 + cl], w1 = W4[1 * 32 + cl];
    float4 w2 = W4[2 * 32 + cl], w3 = W4[3 * 32 + cl];
    for (int k = 0; k < C; k += 4) {
        int kn = (k + 4) & 127;
        float4 nw0 = W4[(kn + 0) * 32 + cl];
        float4 nw1 = W4[(kn + 1) * 32 + cl];
        float4 nw2 = W4[(kn + 2) * 32 + cl];
        float4 nw3 = W4[(kn + 3) * 32 + cl];
        #pragma unroll
        for (int nj = 0; nj < 8; ++nj) {
            float4 zv = *(const float4*)&z[(ng * 8 + nj) * ZSTR + k];
            acc[nj].x += zv.x * w0.x + zv.y * w1.x + zv.z * w2.x + zv.w * w3.x;
            acc[nj].y += zv.x * w0.y + zv.y * w1.y + zv.z * w2.y + zv.w * w3.y;
            acc[nj].z += zv.x * w0.z + zv.y * w1.z + zv.z * w2.z + zv.w * w3.z;
            acc[nj].w += zv.x * w0.w + zv.y * w1.w + zv.z * w2.w + zv.w * w3.w;
        }
        w0 = nw0; w1 = nw1; w2 = nw2; w3 = nw3;
    }
    #pragma unroll
    for (int nj = 0; nj < 8; ++nj) {
        int node = i0 + ng * 8 + nj;
        if (node < n) {
            float4 a = acc[nj];
            a.x = a.x > 0.f ? a.x : SLOPE * a.x;
            a.y = a.y > 0.f ? a.y : SLOPE * a.y;
            a.z = a.z > 0.f ? a.z : SLOPE * a.z;
            a.w = a.w > 0.f ? a.w : SLOPE * a.w;
            ((float4*)xn)[a4(node, cl, n)] = a;
        }
    }
}

// ---------------- dense head: out = (x@wd + bd) @ wo + bo ; xin chunk-major ----------------
__global__ __launch_bounds__(256) void dense_gemm(
    const float* __restrict__ xin, const float* __restrict__ wd, const float* __restrict__ bd,
    const float* __restrict__ wo, const float* __restrict__ bo, float* __restrict__ out, int n)
{
    __shared__ float xr[32 * ZSTR];
    int i0 = blockIdx.x * 32;
    int t = threadIdx.x;
    for (int p = t; p < 32 * 32; p += 256) {
        int r = p >> 5, c4 = p & 31;
        float4 v = {0.f, 0.f, 0.f, 0.f};
        if (i0 + r < n) v = ((const float4*)xin)[a4(i0 + r, c4, n)];
        *(float4*)&xr[r * ZSTR + c4 * 4] = v;
    }
    __syncthreads();

    int cl = t & 63;
    int w = t >> 6;
    float4 acc[8] = {};
    const float4* wd4 = (const float4*)wd;
    float4 w0 = wd4[0 * 64 + cl], w1 = wd4[1 * 64 + cl];
    float4 w2 = wd4[2 * 64 + cl], w3 = wd4[3 * 64 + cl];
    for (int k = 0; k < C; k += 4) {
        int kn = (k + 4) & 127;
        float4 nw0 = wd4[(kn + 0) * 64 + cl];
        float4 nw1 = wd4[(kn + 1) * 64 + cl];
        float4 nw2 = wd4[(kn + 2) * 64 + cl];
        float4 nw3 = wd4[(kn + 3) * 64 + cl];
        #pragma unroll
        for (int nj = 0; nj < 8; ++nj) {
            float4 xv = *(const float4*)&xr[(w * 8 + nj) * ZSTR + k];
            acc[nj].x += xv.x * w0.x + xv.y * w1.x + xv.z * w2.x + xv.w * w3.x;
            acc[nj].y += xv.x * w0.y + xv.y * w1.y + xv.z * w2.y + xv.w * w3.y;
            acc[nj].z += xv.x * w0.z + xv.y * w1.z + xv.z * w2.z + xv.w * w3.z;
            acc[nj].w += xv.x * w0.w + xv.y * w1.w + xv.z * w2.w + xv.w * w3.w;
        }
        w0 = nw0; w1 = nw1; w2 = nw2; w3 = nw3;
    }
    float4 bdv = ((const float4*)bd)[cl];
    const float4* wo4 = (const float4*)wo;
    float4 woa = wo4[cl * 2 + 0];
    float4 wob = wo4[cl * 2 + 1];
    float bo0 = bo[0], bo1 = bo[1];
    #pragma unroll
    for (int nj = 0; nj < 8; ++nj) {
        float4 hid;
        hid.x = acc[nj].x + bdv.x;
        hid.y = acc[nj].y + bdv.y;
        hid.z = acc[nj].z + bdv.z;
        hid.w = acc[nj].w + bdv.w;
        float p0 = hid.x * woa.x + hid.y * woa.z + hid.z * wob.x + hid.w * wob.z;
        float p1 = hid.x * woa.y + hid.y * woa.w + hid.z * wob.y + hid.w * wob.w;
        #pragma unroll
        for (int off = 32; off; off >>= 1) {
            p0 += __shfl_down(p0, off);
            p1 += __shfl_down(p1, off);
        }
        int node = i0 + w * 8 + nj;
        if (cl == 0 && node < n) {
            out[(size_t)node * NOUT + 0] = bo0 + p0;
            out[(size_t)node * NOUT + 1] = bo1 + p1;
        }
    }
}

extern "C" void kernel_launch(void* const* d_in, const int* in_sizes, int n_in,
                              void* d_out, int out_size, void* d_ws, size_t ws_size,
                              hipStream_t stream) {
    const float* x0    = (const float*)d_in[0];
    const int*   ei    = (const int*)d_in[1];
    const float* convW = (const float*)d_in[2];
    const float* wd    = (const float*)d_in[3];
    const float* bd    = (const float*)d_in[4];
    const float* wo    = (const float*)d_in[5];
    const float* bo    = (const float*)d_in[6];
    float* out = (float*)d_out;

    int N = in_sizes[0] / C;
    int E = in_sizes[1] / 2;
    int L = in_sizes[2] / (C * C);
    const int* row = ei;
    const int* col = ei + E;

    char* p = (char*)d_ws;
    auto alloc = [&](size_t bytes) {
        char* r = p;
        p += (bytes + 255) & ~(size_t)255;
        return r;
    };
    int*   cnt    = (int*)alloc((size_t)N * 4);
    int*   offs   = (int*)alloc((size_t)(N + 1) * 4);
    int*   cursor = (int*)alloc((size_t)N * 4);
    int2*  csr    = (int2*)alloc((size_t)E * 8);
    float* dinv   = (float*)alloc((size_t)N * 4);
    float* bufA   = (float*)alloc((size_t)N * C * 4);
    float* bufB   = (float*)alloc((size_t)N * C * 4);

    hipMemsetAsync(cnt, 0, (size_t)N * 4, stream);
    count_kernel<<<(E + 255) / 256, 256, 0, stream>>>(col, cnt, E);
    dinv_kernel<<<(N + 255) / 256, 256, 0, stream>>>(cnt, dinv, N);
    scan_kernel<<<1, 1024, 0, stream>>>(cnt, offs, N);
    copy_kernel<<<(N + 255) / 256, 256, 0, stream>>>(offs, cursor, N);
    fill_kernel<<<(E + 255) / 256, 256, 0, stream>>>(row, col, dinv, cursor, csr, E);
    transpose_kernel<<<(N * 32 + 255) / 256, 256, 0, stream>>>(x0, bufA, N);

    const float* xc = bufA;   // chunk-major
    for (int l = 0; l < L; ++l) {
        float* hbuf = (l & 1) ? bufA : bufB;
        dim3 agrid((N + 3) / 4, NCH);
        agg_kernel<<<agrid, 256, 0, stream>>>(xc, offs, csr, dinv, hbuf, N);
        layer_gemm<<<(N + 63) / 64, 256, 0, stream>>>(hbuf, x0, convW + (size_t)l * C * C,
                                                      hbuf, N);
        xc = hbuf;
    }
    dense_gemm<<<(N + 31) / 32, 256, 0, stream>>>(xc, wd, bd, wo, bo, out, N);
}

// Round 4
// 789.768 us; speedup vs baseline: 1.2109x; 1.2109x over previous
//
#include <hip/hip_runtime.h>
#include <hip/hip_fp16.h>

#define C 128
#define DD 256
#define NOUT 2
#define ALPHA 0.1f
#define SLOPE 0.01f
#define ZSTR 132   // padded LDS row stride (floats)
#define TN 64      // nodes per fused-layer block

// ---------------- graph preprocessing ----------------

__global__ void count_kernel(const int* __restrict__ col, int* __restrict__ cnt, int E) {
    int e = blockIdx.x * 256 + threadIdx.x;
    if (e < E) atomicAdd(&cnt[col[e]], 1);
}

__global__ void dinv_kernel(const int* __restrict__ cnt, float* __restrict__ dinv, int n) {
    int i = blockIdx.x * 256 + threadIdx.x;
    if (i < n) dinv[i] = rsqrtf((float)(cnt[i] + 1));   // +1 self-loop; always > 0
}

// single-block exclusive scan: 1024 threads, 4 elems/thread, shuffle-based
__global__ __launch_bounds__(1024) void scan_kernel(const int* __restrict__ cnt,
                                                    int* __restrict__ offs, int n) {
    __shared__ int wsum[16];
    __shared__ int chunk_carry;
    int t = threadIdx.x;
    int lane = t & 63, wv = t >> 6;
    if (t == 0) chunk_carry = 0;
    __syncthreads();
    for (int base = 0; base < n; base += 4096) {
        int idx = base + t * 4;
        int v0 = (idx + 0 < n) ? cnt[idx + 0] : 0;
        int v1 = (idx + 1 < n) ? cnt[idx + 1] : 0;
        int v2 = (idx + 2 < n) ? cnt[idx + 2] : 0;
        int v3 = (idx + 3 < n) ? cnt[idx + 3] : 0;
        int s0 = v0, s1 = s0 + v1, s2 = s1 + v2, s3 = s2 + v3;
        int tot = s3;
        int sc = tot;
        #pragma unroll
        for (int d = 1; d < 64; d <<= 1) {
            int u = __shfl_up(sc, d);
            if (lane >= d) sc += u;
        }
        if (lane == 63) wsum[wv] = sc;
        __syncthreads();
        int woff = 0;
        #pragma unroll
        for (int j = 0; j < 16; ++j) woff += (j < wv) ? wsum[j] : 0;
        int excl = chunk_carry + woff + (sc - tot);
        if (idx + 0 < n) offs[idx + 0] = excl;
        if (idx + 1 < n) offs[idx + 1] = excl + s0;
        if (idx + 2 < n) offs[idx + 2] = excl + s1;
        if (idx + 3 < n) offs[idx + 3] = excl + s2;
        __syncthreads();
        if (t == 1023) chunk_carry = excl + s3;
        __syncthreads();
    }
    if (t == 0) offs[n] = chunk_carry;
}

__global__ void copy_kernel(const int* __restrict__ src, int* __restrict__ dst, int n) {
    int i = blockIdx.x * 256 + threadIdx.x;
    if (i < n) dst[i] = src[i];
}

// packed edge metadata: {src, float-bits of norm}
__global__ void fill_kernel(const int* __restrict__ row, const int* __restrict__ col,
                            const float* __restrict__ dinv, int* __restrict__ cursor,
                            int2* __restrict__ csr, int E) {
    int e = blockIdx.x * 256 + threadIdx.x;
    if (e >= E) return;
    int r = row[e], c = col[e];
    int pos = atomicAdd(&cursor[c], 1);
    int2 m;
    m.x = r;
    m.y = __float_as_int(dinv[r] * dinv[c]);
    csr[pos] = m;
}

// fp32 node-major -> fp16 node-major
__global__ __launch_bounds__(256) void convert_kernel(const float* __restrict__ x,
                                                      __half* __restrict__ xh, int n) {
    int g = blockIdx.x * 256 + threadIdx.x;
    if (g >= n * 32) return;
    float4 v = ((const float4*)x)[g];
    union { __half2 h; unsigned u; } a, b;
    a.h = __float22half2_rn(make_float2(v.x, v.y));
    b.h = __float22half2_rn(make_float2(v.z, v.w));
    ((uint2*)xh)[g] = make_uint2(a.u, b.u);
}

__device__ __forceinline__ float4 unpack_h4(uint2 hv) {
    union { unsigned u; __half2 h; } a, b;
    a.u = hv.x; b.u = hv.y;
    float2 f0 = __half22float2(a.h), f1 = __half22float2(b.h);
    return make_float4(f0.x, f0.y, f1.x, f1.y);
}

// ---------------- fused layer: gather(fp16) + residual + GEMM(fp32) + LeakyReLU -> fp16
// 256 threads, 64 nodes/block. Gather: 8 half-wave slots, one node at a time,
// 32 lanes x 8B = 256B coalesced row read per edge. Then barrier + register-blocked GEMM.
__global__ __launch_bounds__(256) void layer_fused(
    const __half* __restrict__ xc, const float* __restrict__ x0,
    const float* __restrict__ W, const int* __restrict__ offs,
    const int2* __restrict__ csr, const float* __restrict__ dinv,
    __half* __restrict__ xn, int n)
{
    __shared__ float z[TN * ZSTR];
    int i0 = blockIdx.x * TN;
    int t = threadIdx.x;
    int slot = t >> 5, lane = t & 31;
    const uint2* x2 = (const uint2*)xc;

    #pragma unroll 1
    for (int j = 0; j < 8; ++j) {
        int r = slot * 8 + j;
        int i = i0 + r;
        float4 ga = {0.f, 0.f, 0.f, 0.f};
        if (i < n) {
            int beg = offs[i], end = offs[i + 1];
            for (int k = beg; k < end; ++k) {
                int2 m = csr[k];                          // lane-uniform -> broadcast
                float w = __int_as_float(m.y);
                float4 v = unpack_h4(x2[(size_t)m.x * 32 + lane]);
                ga.x += w * v.x; ga.y += w * v.y; ga.z += w * v.z; ga.w += w * v.w;
            }
            float di = dinv[i], w0 = di * di;
            float4 s = unpack_h4(x2[(size_t)i * 32 + lane]);
            float4 xv = ((const float4*)x0)[(size_t)i * 32 + lane];
            ga.x = (1.f - ALPHA) * (ga.x + w0 * s.x) + ALPHA * xv.x;
            ga.y = (1.f - ALPHA) * (ga.y + w0 * s.y) + ALPHA * xv.y;
            ga.z = (1.f - ALPHA) * (ga.z + w0 * s.z) + ALPHA * xv.z;
            ga.w = (1.f - ALPHA) * (ga.w + w0 * s.w) + ALPHA * xv.w;
        }
        *(float4*)&z[r * ZSTR + lane * 4] = ga;
    }
    __syncthreads();

    // GEMM: thread = (col-group cl -> 4 cols, node-group ng -> 8 nodes)
    int cl = t & 31;
    int ng = t >> 5;
    float4 acc[8] = {};
    const float4* W4 = (const float4*)W;
    float4 w0 = W4[0 * 32 + cl], w1 = W4[1 * 32 + cl];
    float4 w2 = W4[2 * 32 + cl], w3 = W4[3 * 32 + cl];
    for (int k = 0; k < C; k += 4) {
        int kn = (k + 4) & 127;     // wrap avoids OOB; redundant load at tail
        float4 nw0 = W4[(kn + 0) * 32 + cl];
        float4 nw1 = W4[(kn + 1) * 32 + cl];
        float4 nw2 = W4[(kn + 2) * 32 + cl];
        float4 nw3 = W4[(kn + 3) * 32 + cl];
        #pragma unroll
        for (int nj = 0; nj < 8; ++nj) {
            float4 zv = *(const float4*)&z[(ng * 8 + nj) * ZSTR + k];
            acc[nj].x += zv.x * w0.x + zv.y * w1.x + zv.z * w2.x + zv.w * w3.x;
            acc[nj].y += zv.x * w0.y + zv.y * w1.y + zv.z * w2.y + zv.w * w3.y;
            acc[nj].z += zv.x * w0.z + zv.y * w1.z + zv.z * w2.z + zv.w * w3.z;
            acc[nj].w += zv.x * w0.w + zv.y * w1.w + zv.z * w2.w + zv.w * w3.w;
        }
        w0 = nw0; w1 = nw1; w2 = nw2; w3 = nw3;
    }
    #pragma unroll
    for (int nj = 0; nj < 8; ++nj) {
        int node = i0 + ng * 8 + nj;
        if (node < n) {
            float4 a = acc[nj];
            a.x = a.x > 0.f ? a.x : SLOPE * a.x;
            a.y = a.y > 0.f ? a.y : SLOPE * a.y;
            a.z = a.z > 0.f ? a.z : SLOPE * a.z;
            a.w = a.w > 0.f ? a.w : SLOPE * a.w;
            union { __half2 h; unsigned u; } pa, pb;
            pa.h = __float22half2_rn(make_float2(a.x, a.y));
            pb.h = __float22half2_rn(make_float2(a.z, a.w));
            ((uint2*)xn)[(size_t)node * 32 + cl] = make_uint2(pa.u, pb.u);
        }
    }
}

// ---------------- dense head: out = (x@wd + bd) @ wo + bo ; xin fp16 ----------------
__global__ __launch_bounds__(256) void dense_gemm(
    const __half* __restrict__ xin, const float* __restrict__ wd, const float* __restrict__ bd,
    const float* __restrict__ wo, const float* __restrict__ bo, float* __restrict__ out, int n)
{
    __shared__ float xr[32 * ZSTR];
    int i0 = blockIdx.x * 32;
    int t = threadIdx.x;
    for (int p = t; p < 32 * 32; p += 256) {
        int r = p >> 5, c4 = p & 31;
        float4 v = {0.f, 0.f, 0.f, 0.f};
        if (i0 + r < n) v = unpack_h4(((const uint2*)xin)[(size_t)(i0 + r) * 32 + c4]);
        *(float4*)&xr[r * ZSTR + c4 * 4] = v;
    }
    __syncthreads();

    int cl = t & 63;
    int w = t >> 6;
    float4 acc[8] = {};
    const float4* wd4 = (const float4*)wd;
    float4 w0 = wd4[0 * 64 + cl], w1 = wd4[1 * 64 + cl];
    float4 w2 = wd4[2 * 64 + cl], w3 = wd4[3 * 64 + cl];
    for (int k = 0; k < C; k += 4) {
        int kn = (k + 4) & 127;
        float4 nw0 = wd4[(kn + 0) * 64 + cl];
        float4 nw1 = wd4[(kn + 1) * 64 + cl];
        float4 nw2 = wd4[(kn + 2) * 64 + cl];
        float4 nw3 = wd4[(kn + 3) * 64 + cl];
        #pragma unroll
        for (int nj = 0; nj < 8; ++nj) {
            float4 xv = *(const float4*)&xr[(w * 8 + nj) * ZSTR + k];
            acc[nj].x += xv.x * w0.x + xv.y * w1.x + xv.z * w2.x + xv.w * w3.x;
            acc[nj].y += xv.x * w0.y + xv.y * w1.y + xv.z * w2.y + xv.w * w3.y;
            acc[nj].z += xv.x * w0.z + xv.y * w1.z + xv.z * w2.z + xv.w * w3.z;
            acc[nj].w += xv.x * w0.w + xv.y * w1.w + xv.z * w2.w + xv.w * w3.w;
        }
        w0 = nw0; w1 = nw1; w2 = nw2; w3 = nw3;
    }
    float4 bdv = ((const float4*)bd)[cl];
    const float4* wo4 = (const float4*)wo;
    float4 woa = wo4[cl * 2 + 0];
    float4 wob = wo4[cl * 2 + 1];
    float bo0 = bo[0], bo1 = bo[1];
    #pragma unroll
    for (int nj = 0; nj < 8; ++nj) {
        float4 hid;
        hid.x = acc[nj].x + bdv.x;
        hid.y = acc[nj].y + bdv.y;
        hid.z = acc[nj].z + bdv.z;
        hid.w = acc[nj].w + bdv.w;
        float p0 = hid.x * woa.x + hid.y * woa.z + hid.z * wob.x + hid.w * wob.z;
        float p1 = hid.x * woa.y + hid.y * woa.w + hid.z * wob.y + hid.w * wob.w;
        #pragma unroll
        for (int off = 32; off; off >>= 1) {
            p0 += __shfl_down(p0, off);
            p1 += __shfl_down(p1, off);
        }
        int node = i0 + w * 8 + nj;
        if (cl == 0 && node < n) {
            out[(size_t)node * NOUT + 0] = bo0 + p0;
            out[(size_t)node * NOUT + 1] = bo1 + p1;
        }
    }
}

extern "C" void kernel_launch(void* const* d_in, const int* in_sizes, int n_in,
                              void* d_out, int out_size, void* d_ws, size_t ws_size,
                              hipStream_t stream) {
    const float* x0    = (const float*)d_in[0];
    const int*   ei    = (const int*)d_in[1];
    const float* convW = (const float*)d_in[2];
    const float* wd    = (const float*)d_in[3];
    const float* bd    = (const float*)d_in[4];
    const float* wo    = (const float*)d_in[5];
    const float* bo    = (const float*)d_in[6];
    float* out = (float*)d_out;

    int N = in_sizes[0] / C;
    int E = in_sizes[1] / 2;
    int L = in_sizes[2] / (C * C);
    const int* row = ei;
    const int* col = ei + E;

    char* p = (char*)d_ws;
    auto alloc = [&](size_t bytes) {
        char* r = p;
        p += (bytes + 255) & ~(size_t)255;
        return r;
    };
    int*    cnt    = (int*)alloc((size_t)N * 4);
    int*    offs   = (int*)alloc((size_t)(N + 1) * 4);
    int*    cursor = (int*)alloc((size_t)N * 4);
    int2*   csr    = (int2*)alloc((size_t)E * 8);
    float*  dinv   = (float*)alloc((size_t)N * 4);
    __half* bufA   = (__half*)alloc((size_t)N * C * 2);
    __half* bufB   = (__half*)alloc((size_t)N * C * 2);

    hipMemsetAsync(cnt, 0, (size_t)N * 4, stream);
    count_kernel<<<(E + 255) / 256, 256, 0, stream>>>(col, cnt, E);
    dinv_kernel<<<(N + 255) / 256, 256, 0, stream>>>(cnt, dinv, N);
    scan_kernel<<<1, 1024, 0, stream>>>(cnt, offs, N);
    copy_kernel<<<(N + 255) / 256, 256, 0, stream>>>(offs, cursor, N);
    fill_kernel<<<(E + 255) / 256, 256, 0, stream>>>(row, col, dinv, cursor, csr, E);
    convert_kernel<<<(N * 32 + 255) / 256, 256, 0, stream>>>(x0, bufA, N);

    const __half* xc = bufA;
    for (int l = 0; l < L; ++l) {
        __half* nxt = (l & 1) ? bufA : bufB;
        layer_fused<<<(N + TN - 1) / TN, 256, 0, stream>>>(
            xc, x0, convW + (size_t)l * C * C, offs, csr, dinv, nxt, N);
        xc = nxt;
    }
    dense_gemm<<<(N + 31) / 32, 256, 0, stream>>>(xc, wd, bd, wo, bo, out, N);
}

// Round 5
// 562.685 us; speedup vs baseline: 1.6996x; 1.4036x over previous
//
#include <hip/hip_runtime.h>
#include <hip/hip_fp16.h>

#define C 128
#define NOUT 2
#define ALPHA 0.1f
#define SLOPE 0.01f
#define ZSTR 132   // padded LDS row stride (floats)
#define TN 32      // nodes per fused-layer block

// ---------------- graph preprocessing ----------------

__global__ void count_kernel(const int* __restrict__ col, int* __restrict__ cnt, int E) {
    int e = blockIdx.x * 256 + threadIdx.x;
    if (e < E) atomicAdd(&cnt[col[e]], 1);
}

// per-1024-chunk exclusive scan + chunk totals; also computes dinv
__global__ __launch_bounds__(1024) void scanA_kernel(const int* __restrict__ cnt,
                                                     int* __restrict__ offs,
                                                     int* __restrict__ bsum,
                                                     float* __restrict__ dinv, int n) {
    __shared__ int wsum[16];
    int t = threadIdx.x, lane = t & 63, wv = t >> 6;
    int i = blockIdx.x * 1024 + t;
    int v = (i < n) ? cnt[i] : 0;
    if (i < n) dinv[i] = rsqrtf((float)(v + 1));   // +1 self-loop
    int sc = v;
    #pragma unroll
    for (int d = 1; d < 64; d <<= 1) {
        int u = __shfl_up(sc, d);
        if (lane >= d) sc += u;
    }
    if (lane == 63) wsum[wv] = sc;
    __syncthreads();
    int woff = 0;
    #pragma unroll
    for (int j = 0; j < 16; ++j) woff += (j < wv) ? wsum[j] : 0;
    if (i < n) offs[i] = woff + sc - v;            // block-local exclusive
    if (t == 0) {
        int tot = 0;
        #pragma unroll
        for (int j = 0; j < 16; ++j) tot += wsum[j];
        bsum[blockIdx.x] = tot;
    }
}

// single block: exclusive scan of up to 1024 chunk totals
__global__ __launch_bounds__(1024) void scanB_kernel(const int* __restrict__ bsum,
                                                     int* __restrict__ bbase, int nb) {
    __shared__ int wsum[16];
    int t = threadIdx.x, lane = t & 63, wv = t >> 6;
    int v = (t < nb) ? bsum[t] : 0;
    int sc = v;
    #pragma unroll
    for (int d = 1; d < 64; d <<= 1) {
        int u = __shfl_up(sc, d);
        if (lane >= d) sc += u;
    }
    if (lane == 63) wsum[wv] = sc;
    __syncthreads();
    int woff = 0;
    #pragma unroll
    for (int j = 0; j < 16; ++j) woff += (j < wv) ? wsum[j] : 0;
    if (t < nb) bbase[t] = woff + sc - v;
}

// finalize: offs += chunk base; cursor = offs; offs[n] = E
__global__ void scanC_kernel(int* __restrict__ offs, int* __restrict__ cursor,
                             const int* __restrict__ bbase, int n, int E) {
    int i = blockIdx.x * 256 + threadIdx.x;
    if (i < n) {
        int o = offs[i] + bbase[i >> 10];
        offs[i] = o;
        cursor[i] = o;
    }
    if (i == n) offs[n] = E;
}

// packed edge metadata: {src, float-bits of norm}
__global__ void fill_kernel(const int* __restrict__ row, const int* __restrict__ col,
                            const float* __restrict__ dinv, int* __restrict__ cursor,
                            int2* __restrict__ csr, int E) {
    int e = blockIdx.x * 256 + threadIdx.x;
    if (e >= E) return;
    int r = row[e], c = col[e];
    int pos = atomicAdd(&cursor[c], 1);
    int2 m;
    m.x = r;
    m.y = __float_as_int(dinv[r] * dinv[c]);
    csr[pos] = m;
}

// fp32 node-major -> fp16 node-major
__global__ __launch_bounds__(256) void convert_kernel(const float* __restrict__ x,
                                                      __half* __restrict__ xh, int n) {
    int g = blockIdx.x * 256 + threadIdx.x;
    if (g >= n * 32) return;
    float4 v = ((const float4*)x)[g];
    union { __half2 h; unsigned u; } a, b;
    a.h = __float22half2_rn(make_float2(v.x, v.y));
    b.h = __float22half2_rn(make_float2(v.z, v.w));
    ((uint2*)xh)[g] = make_uint2(a.u, b.u);
}

__device__ __forceinline__ float4 unpack_h4(uint2 hv) {
    union { unsigned u; __half2 h; } a, b;
    a.u = hv.x; b.u = hv.y;
    float2 f0 = __half22float2(a.h), f1 = __half22float2(b.h);
    return make_float4(f0.x, f0.y, f1.x, f1.y);
}

// ---------------- fused layer: gather(fp16, unroll-4) + residual + GEMM(fp32) -> fp16
// 256 threads, 32 nodes/block; gather: 8 half-waves x 4 nodes, 4 edges in flight each
__global__ __launch_bounds__(256) void layer_fused(
    const __half* __restrict__ xc, const __half* __restrict__ x0h,
    const float* __restrict__ W, const int* __restrict__ offs,
    const int2* __restrict__ csr, const float* __restrict__ dinv,
    __half* __restrict__ xn, int n)
{
    __shared__ float z[TN * ZSTR];
    int i0 = blockIdx.x * TN;
    int t = threadIdx.x;
    int slot = t >> 5, lane = t & 31;
    const uint2* x2 = (const uint2*)xc;
    const uint2* x02 = (const uint2*)x0h;

    #pragma unroll 1
    for (int j = 0; j < 4; ++j) {
        int r = slot * 4 + j;
        int i = i0 + r;
        float4 a0 = {0.f,0.f,0.f,0.f}, a1 = a0, a2 = a0, a3 = a0;
        if (i < n) {
            int beg = offs[i], end = offs[i + 1];
            int k = beg;
            for (; k + 4 <= end; k += 4) {
                int2 m0 = csr[k + 0], m1 = csr[k + 1], m2 = csr[k + 2], m3 = csr[k + 3];
                uint2 q0 = x2[(size_t)m0.x * 32 + lane];
                uint2 q1 = x2[(size_t)m1.x * 32 + lane];
                uint2 q2 = x2[(size_t)m2.x * 32 + lane];
                uint2 q3 = x2[(size_t)m3.x * 32 + lane];
                float w0 = __int_as_float(m0.y), w1 = __int_as_float(m1.y);
                float w2 = __int_as_float(m2.y), w3 = __int_as_float(m3.y);
                float4 v0 = unpack_h4(q0), v1 = unpack_h4(q1);
                float4 v2 = unpack_h4(q2), v3 = unpack_h4(q3);
                a0.x += w0 * v0.x; a0.y += w0 * v0.y; a0.z += w0 * v0.z; a0.w += w0 * v0.w;
                a1.x += w1 * v1.x; a1.y += w1 * v1.y; a1.z += w1 * v1.z; a1.w += w1 * v1.w;
                a2.x += w2 * v2.x; a2.y += w2 * v2.y; a2.z += w2 * v2.z; a2.w += w2 * v2.w;
                a3.x += w3 * v3.x; a3.y += w3 * v3.y; a3.z += w3 * v3.z; a3.w += w3 * v3.w;
            }
            for (; k < end; ++k) {
                int2 m = csr[k];
                float w = __int_as_float(m.y);
                float4 v = unpack_h4(x2[(size_t)m.x * 32 + lane]);
                a0.x += w * v.x; a0.y += w * v.y; a0.z += w * v.z; a0.w += w * v.w;
            }
            float di = dinv[i], sw = di * di;
            float4 s = unpack_h4(x2[(size_t)i * 32 + lane]);
            float4 xv = unpack_h4(x02[(size_t)i * 32 + lane]);
            a0.x = (1.f - ALPHA) * (a0.x + a1.x + a2.x + a3.x + sw * s.x) + ALPHA * xv.x;
            a0.y = (1.f - ALPHA) * (a0.y + a1.y + a2.y + a3.y + sw * s.y) + ALPHA * xv.y;
            a0.z = (1.f - ALPHA) * (a0.z + a1.z + a2.z + a3.z + sw * s.z) + ALPHA * xv.z;
            a0.w = (1.f - ALPHA) * (a0.w + a1.w + a2.w + a3.w + sw * s.w) + ALPHA * xv.w;
        }
        *(float4*)&z[r * ZSTR + lane * 4] = a0;
    }
    __syncthreads();

    // GEMM: thread = (cl -> 4 cols, ng -> 4 nodes)
    int cl = t & 31;
    int ng = t >> 5;
    float4 acc[4] = {};
    const float4* W4 = (const float4*)W;
    float4 w0 = W4[0 * 32 + cl], w1 = W4[1 * 32 + cl];
    float4 w2 = W4[2 * 32 + cl], w3 = W4[3 * 32 + cl];
    for (int k = 0; k < C; k += 4) {
        int kn = (k + 4) & 127;     // wrap avoids OOB; redundant load at tail
        float4 nw0 = W4[(kn + 0) * 32 + cl];
        float4 nw1 = W4[(kn + 1) * 32 + cl];
        float4 nw2 = W4[(kn + 2) * 32 + cl];
        float4 nw3 = W4[(kn + 3) * 32 + cl];
        #pragma unroll
        for (int nj = 0; nj < 4; ++nj) {
            float4 zv = *(const float4*)&z[(ng * 4 + nj) * ZSTR + k];
            acc[nj].x += zv.x * w0.x + zv.y * w1.x + zv.z * w2.x + zv.w * w3.x;
            acc[nj].y += zv.x * w0.y + zv.y * w1.y + zv.z * w2.y + zv.w * w3.y;
            acc[nj].z += zv.x * w0.z + zv.y * w1.z + zv.z * w2.z + zv.w * w3.z;
            acc[nj].w += zv.x * w0.w + zv.y * w1.w + zv.z * w2.w + zv.w * w3.w;
        }
        w0 = nw0; w1 = nw1; w2 = nw2; w3 = nw3;
    }
    #pragma unroll
    for (int nj = 0; nj < 4; ++nj) {
        int node = i0 + ng * 4 + nj;
        if (node < n) {
            float4 a = acc[nj];
            a.x = a.x > 0.f ? a.x : SLOPE * a.x;
            a.y = a.y > 0.f ? a.y : SLOPE * a.y;
            a.z = a.z > 0.f ? a.z : SLOPE * a.z;
            a.w = a.w > 0.f ? a.w : SLOPE * a.w;
            union { __half2 h; unsigned u; } pa, pb;
            pa.h = __float22half2_rn(make_float2(a.x, a.y));
            pb.h = __float22half2_rn(make_float2(a.z, a.w));
            ((uint2*)xn)[(size_t)node * 32 + cl] = make_uint2(pa.u, pb.u);
        }
    }
}

// ---------------- dense head: out = (x@wd + bd) @ wo + bo ; xin fp16 ----------------
__global__ __launch_bounds__(256) void dense_gemm(
    const __half* __restrict__ xin, const float* __restrict__ wd, const float* __restrict__ bd,
    const float* __restrict__ wo, const float* __restrict__ bo, float* __restrict__ out, int n)
{
    __shared__ float xr[32 * ZSTR];
    int i0 = blockIdx.x * 32;
    int t = threadIdx.x;
    for (int p = t; p < 32 * 32; p += 256) {
        int r = p >> 5, c4 = p & 31;
        float4 v = {0.f, 0.f, 0.f, 0.f};
        if (i0 + r < n) v = unpack_h4(((const uint2*)xin)[(size_t)(i0 + r) * 32 + c4]);
        *(float4*)&xr[r * ZSTR + c4 * 4] = v;
    }
    __syncthreads();

    int cl = t & 63;
    int w = t >> 6;
    float4 acc[8] = {};
    const float4* wd4 = (const float4*)wd;
    float4 w0 = wd4[0 * 64 + cl], w1 = wd4[1 * 64 + cl];
    float4 w2 = wd4[2 * 64 + cl], w3 = wd4[3 * 64 + cl];
    for (int k = 0; k < C; k += 4) {
        int kn = (k + 4) & 127;
        float4 nw0 = wd4[(kn + 0) * 64 + cl];
        float4 nw1 = wd4[(kn + 1) * 64 + cl];
        float4 nw2 = wd4[(kn + 2) * 64 + cl];
        float4 nw3 = wd4[(kn + 3) * 64 + cl];
        #pragma unroll
        for (int nj = 0; nj < 8; ++nj) {
            float4 xv = *(const float4*)&xr[(w * 8 + nj) * ZSTR + k];
            acc[nj].x += xv.x * w0.x + xv.y * w1.x + xv.z * w2.x + xv.w * w3.x;
            acc[nj].y += xv.x * w0.y + xv.y * w1.y + xv.z * w2.y + xv.w * w3.y;
            acc[nj].z += xv.x * w0.z + xv.y * w1.z + xv.z * w2.z + xv.w * w3.z;
            acc[nj].w += xv.x * w0.w + xv.y * w1.w + xv.z * w2.w + xv.w * w3.w;
        }
        w0 = nw0; w1 = nw1; w2 = nw2; w3 = nw3;
    }
    float4 bdv = ((const float4*)bd)[cl];
    const float4* wo4 = (const float4*)wo;
    float4 woa = wo4[cl * 2 + 0];
    float4 wob = wo4[cl * 2 + 1];
    float bo0 = bo[0], bo1 = bo[1];
    #pragma unroll
    for (int nj = 0; nj < 8; ++nj) {
        float4 hid;
        hid.x = acc[nj].x + bdv.x;
        hid.y = acc[nj].y + bdv.y;
        hid.z = acc[nj].z + bdv.z;
        hid.w = acc[nj].w + bdv.w;
        float p0 = hid.x * woa.x + hid.y * woa.z + hid.z * wob.x + hid.w * wob.z;
        float p1 = hid.x * woa.y + hid.y * woa.w + hid.z * wob.y + hid.w * wob.w;
        #pragma unroll
        for (int off = 32; off; off >>= 1) {
            p0 += __shfl_down(p0, off);
            p1 += __shfl_down(p1, off);
        }
        int node = i0 + w * 8 + nj;
        if (cl == 0 && node < n) {
            out[(size_t)node * NOUT + 0] = bo0 + p0;
            out[(size_t)node * NOUT + 1] = bo1 + p1;
        }
    }
}

extern "C" void kernel_launch(void* const* d_in, const int* in_sizes, int n_in,
                              void* d_out, int out_size, void* d_ws, size_t ws_size,
                              hipStream_t stream) {
    const float* x0    = (const float*)d_in[0];
    const int*   ei    = (const int*)d_in[1];
    const float* convW = (const float*)d_in[2];
    const float* wd    = (const float*)d_in[3];
    const float* bd    = (const float*)d_in[4];
    const float* wo    = (const float*)d_in[5];
    const float* bo    = (const float*)d_in[6];
    float* out = (float*)d_out;

    int N = in_sizes[0] / C;
    int E = in_sizes[1] / 2;
    int L = in_sizes[2] / (C * C);
    const int* row = ei;
    const int* col = ei + E;
    int NB = (N + 1023) / 1024;

    char* p = (char*)d_ws;
    auto alloc = [&](size_t bytes) {
        char* r = p;
        p += (bytes + 255) & ~(size_t)255;
        return r;
    };
    int*    cnt    = (int*)alloc((size_t)N * 4);
    int*    offs   = (int*)alloc((size_t)(N + 1) * 4);
    int*    cursor = (int*)alloc((size_t)N * 4);
    int*    bsum   = (int*)alloc((size_t)NB * 4);
    int*    bbase  = (int*)alloc((size_t)NB * 4);
    int2*   csr    = (int2*)alloc((size_t)E * 8);
    float*  dinv   = (float*)alloc((size_t)N * 4);
    __half* x0h    = (__half*)alloc((size_t)N * C * 2);
    __half* bufA   = (__half*)alloc((size_t)N * C * 2);
    __half* bufB   = (__half*)alloc((size_t)N * C * 2);

    hipMemsetAsync(cnt, 0, (size_t)N * 4, stream);
    count_kernel<<<(E + 255) / 256, 256, 0, stream>>>(col, cnt, E);
    scanA_kernel<<<NB, 1024, 0, stream>>>(cnt, offs, bsum, dinv, N);
    scanB_kernel<<<1, 1024, 0, stream>>>(bsum, bbase, NB);
    scanC_kernel<<<(N + 256) / 256, 256, 0, stream>>>(offs, cursor, bbase, N, E);
    fill_kernel<<<(E + 255) / 256, 256, 0, stream>>>(row, col, dinv, cursor, csr, E);
    convert_kernel<<<(N * 32 + 255) / 256, 256, 0, stream>>>(x0, x0h, N);

    const __half* xc = x0h;
    for (int l = 0; l < L; ++l) {
        __half* nxt = (l & 1) ? bufB : bufA;
        layer_fused<<<(N + TN - 1) / TN, 256, 0, stream>>>(
            xc, x0h, convW + (size_t)l * C * C, offs, csr, dinv, nxt, N);
        xc = nxt;
    }
    dense_gemm<<<(N + 31) / 32, 256, 0, stream>>>(xc, wd, bd, wo, bo, out, N);
}

// Round 6
// 477.598 us; speedup vs baseline: 2.0024x; 1.1782x over previous
//
#include <hip/hip_runtime.h>
#include <hip/hip_fp16.h>

#define C 128
#define NOUT 2
#define ALPHA 0.1f
#define SLOPE 0.01f
#define ZSTR 132   // padded LDS row stride (floats)

// ---------------- graph preprocessing ----------------

__global__ void count_kernel(const int* __restrict__ col, int* __restrict__ cnt, int E) {
    int e = blockIdx.x * 256 + threadIdx.x;
    if (e < E) atomicAdd(&cnt[col[e]], 1);
}

// per-1024-chunk exclusive scan + chunk totals; also computes dinv
__global__ __launch_bounds__(1024) void scanA_kernel(const int* __restrict__ cnt,
                                                     int* __restrict__ offs,
                                                     int* __restrict__ bsum,
                                                     float* __restrict__ dinv, int n) {
    __shared__ int wsum[16];
    int t = threadIdx.x, lane = t & 63, wv = t >> 6;
    int i = blockIdx.x * 1024 + t;
    int v = (i < n) ? cnt[i] : 0;
    if (i < n) dinv[i] = rsqrtf((float)(v + 1));   // +1 self-loop
    int sc = v;
    #pragma unroll
    for (int d = 1; d < 64; d <<= 1) {
        int u = __shfl_up(sc, d);
        if (lane >= d) sc += u;
    }
    if (lane == 63) wsum[wv] = sc;
    __syncthreads();
    int woff = 0;
    #pragma unroll
    for (int j = 0; j < 16; ++j) woff += (j < wv) ? wsum[j] : 0;
    if (i < n) offs[i] = woff + sc - v;            // block-local exclusive
    if (t == 0) {
        int tot = 0;
        #pragma unroll
        for (int j = 0; j < 16; ++j) tot += wsum[j];
        bsum[blockIdx.x] = tot;
    }
}

// single block: exclusive scan of up to 1024 chunk totals
__global__ __launch_bounds__(1024) void scanB_kernel(const int* __restrict__ bsum,
                                                     int* __restrict__ bbase, int nb) {
    __shared__ int wsum[16];
    int t = threadIdx.x, lane = t & 63, wv = t >> 6;
    int v = (t < nb) ? bsum[t] : 0;
    int sc = v;
    #pragma unroll
    for (int d = 1; d < 64; d <<= 1) {
        int u = __shfl_up(sc, d);
        if (lane >= d) sc += u;
    }
    if (lane == 63) wsum[wv] = sc;
    __syncthreads();
    int woff = 0;
    #pragma unroll
    for (int j = 0; j < 16; ++j) woff += (j < wv) ? wsum[j] : 0;
    if (t < nb) bbase[t] = woff + sc - v;
}

// finalize: offs += chunk base; cursor = offs; offs[n] = E
__global__ void scanC_kernel(int* __restrict__ offs, int* __restrict__ cursor,
                             const int* __restrict__ bbase, int n, int E) {
    int i = blockIdx.x * 256 + threadIdx.x;
    if (i < n) {
        int o = offs[i] + bbase[i >> 10];
        offs[i] = o;
        cursor[i] = o;
    }
    if (i == n) offs[n] = E;
}

// packed edge metadata: {src, float-bits of norm}
__global__ void fill_kernel(const int* __restrict__ row, const int* __restrict__ col,
                            const float* __restrict__ dinv, int* __restrict__ cursor,
                            int2* __restrict__ csr, int E) {
    int e = blockIdx.x * 256 + threadIdx.x;
    if (e >= E) return;
    int r = row[e], c = col[e];
    int pos = atomicAdd(&cursor[c], 1);
    int2 m;
    m.x = r;
    m.y = __float_as_int(dinv[r] * dinv[c]);
    csr[pos] = m;
}

// fp32 node-major -> fp16 node-major
__global__ __launch_bounds__(256) void convert_kernel(const float* __restrict__ x,
                                                      __half* __restrict__ xh, int n) {
    int g = blockIdx.x * 256 + threadIdx.x;
    if (g >= n * 32) return;
    float4 v = ((const float4*)x)[g];
    union { __half2 h; unsigned u; } a, b;
    a.h = __float22half2_rn(make_float2(v.x, v.y));
    b.h = __float22half2_rn(make_float2(v.z, v.w));
    ((uint2*)xh)[g] = make_uint2(a.u, b.u);
}

__device__ __forceinline__ float4 unpack_h4(uint2 hv) {
    union { unsigned u; __half2 h; } a, b;
    a.u = hv.x; b.u = hv.y;
    float2 f0 = __half22float2(a.h), f1 = __half22float2(b.h);
    return make_float4(f0.x, f0.y, f1.x, f1.y);
}

__device__ __forceinline__ void accum8(float* a, uint4 q, float w) {
    union { unsigned u; __half2 h; } c;
    float2 f;
    c.u = q.x; f = __half22float2(c.h); a[0] += w * f.x; a[1] += w * f.y;
    c.u = q.y; f = __half22float2(c.h); a[2] += w * f.x; a[3] += w * f.y;
    c.u = q.z; f = __half22float2(c.h); a[4] += w * f.x; a[5] += w * f.y;
    c.u = q.w; f = __half22float2(c.h); a[6] += w * f.x; a[7] += w * f.y;
}

__device__ __forceinline__ uint4 pack8(const float* a) {
    union { __half2 h; unsigned u; } c0, c1, c2, c3;
    c0.h = __float22half2_rn(make_float2(a[0], a[1]));
    c1.h = __float22half2_rn(make_float2(a[2], a[3]));
    c2.h = __float22half2_rn(make_float2(a[4], a[5]));
    c3.h = __float22half2_rn(make_float2(a[6], a[7]));
    return make_uint4(c0.u, c1.u, c2.u, c3.u);
}

// ---------------- aggregation: h[i] = sum_j norm*x[j] + dinv(i)^2*x[i]  (fp16 in/out)
// one wave per node; lane = eslot(0..3) x chan-group(0..15); uint4 = 8 fp16 per lane;
// edge loop unroll-2 -> 8 rows in flight per wave; no LDS.
__global__ __launch_bounds__(256) void agg_kernel(
    const __half* __restrict__ xc, const int* __restrict__ offs,
    const int2* __restrict__ csr, const float* __restrict__ dinv,
    __half* __restrict__ h, int n)
{
    int node = blockIdx.x * 4 + (threadIdx.x >> 6);
    if (node >= n) return;
    int lane = threadIdx.x & 63;
    int eslot = lane >> 4, cg = lane & 15;
    const uint4* x4 = (const uint4*)xc;    // 16 uint4 per 128-fp16 row
    float a0[8] = {}, a1[8] = {};
    int beg = offs[node], end = offs[node + 1];
    int k = beg + eslot;
    while (k + 4 < end) {
        int2 m0 = csr[k], m1 = csr[k + 4];
        uint4 q0 = x4[(size_t)m0.x * 16 + cg];
        uint4 q1 = x4[(size_t)m1.x * 16 + cg];
        accum8(a0, q0, __int_as_float(m0.y));
        accum8(a1, q1, __int_as_float(m1.y));
        k += 8;
    }
    if (k < end) {
        int2 m = csr[k];
        uint4 q = x4[(size_t)m.x * 16 + cg];
        accum8(a0, q, __int_as_float(m.y));
    }
    #pragma unroll
    for (int j = 0; j < 8; ++j) a0[j] += a1[j];
    #pragma unroll
    for (int j = 0; j < 8; ++j) {
        a0[j] += __shfl_xor(a0[j], 16);
        a0[j] += __shfl_xor(a0[j], 32);
    }
    if (eslot == 0) {
        float di = dinv[node], sw = di * di;
        uint4 qs = x4[(size_t)node * 16 + cg];
        accum8(a0, qs, sw);
        ((uint4*)h)[(size_t)node * 16 + cg] = pack8(a0);
    }
}

// ---------------- layer GEMM: xn = leaky(((1-a)h + a*x0) @ W) ; fp16 io, in-place ok
__global__ __launch_bounds__(256) void layer_gemm(
    const __half* __restrict__ h, const __half* __restrict__ x0h,
    const float* __restrict__ W, __half* __restrict__ xn, int n)
{
    __shared__ float z[64 * ZSTR];
    int i0 = blockIdx.x * 64;
    int t = threadIdx.x;
    for (int p = t; p < 64 * 32; p += 256) {
        int r = p >> 5, c4 = p & 31;
        float4 zv = {0.f, 0.f, 0.f, 0.f};
        if (i0 + r < n) {
            size_t gi = (size_t)(i0 + r) * 32 + c4;
            float4 hv = unpack_h4(((const uint2*)h)[gi]);
            float4 xv = unpack_h4(((const uint2*)x0h)[gi]);
            zv.x = (1.f - ALPHA) * hv.x + ALPHA * xv.x;
            zv.y = (1.f - ALPHA) * hv.y + ALPHA * xv.y;
            zv.z = (1.f - ALPHA) * hv.z + ALPHA * xv.z;
            zv.w = (1.f - ALPHA) * hv.w + ALPHA * xv.w;
        }
        *(float4*)&z[r * ZSTR + c4 * 4] = zv;
    }
    __syncthreads();

    int cl = t & 31;    // cols 4*cl..4*cl+3
    int ng = t >> 5;    // nodes ng*8..ng*8+7
    float4 acc[8] = {};
    const float4* W4 = (const float4*)W;
    float4 w0 = W4[0 * 32 + cl], w1 = W4[1 * 32 + cl];
    float4 w2 = W4[2 * 32 + cl], w3 = W4[3 * 32 + cl];
    for (int k = 0; k < C; k += 4) {
        int kn = (k + 4) & 127;     // wrap avoids OOB; redundant load at tail
        float4 nw0 = W4[(kn + 0) * 32 + cl];
        float4 nw1 = W4[(kn + 1) * 32 + cl];
        float4 nw2 = W4[(kn + 2) * 32 + cl];
        float4 nw3 = W4[(kn + 3) * 32 + cl];
        #pragma unroll
        for (int nj = 0; nj < 8; ++nj) {
            float4 zv = *(const float4*)&z[(ng * 8 + nj) * ZSTR + k];
            acc[nj].x += zv.x * w0.x + zv.y * w1.x + zv.z * w2.x + zv.w * w3.x;
            acc[nj].y += zv.x * w0.y + zv.y * w1.y + zv.z * w2.y + zv.w * w3.y;
            acc[nj].z += zv.x * w0.z + zv.y * w1.z + zv.z * w2.z + zv.w * w3.z;
            acc[nj].w += zv.x * w0.w + zv.y * w1.w + zv.z * w2.w + zv.w * w3.w;
        }
        w0 = nw0; w1 = nw1; w2 = nw2; w3 = nw3;
    }
    #pragma unroll
    for (int nj = 0; nj < 8; ++nj) {
        int node = i0 + ng * 8 + nj;
        if (node < n) {
            float4 a = acc[nj];
            a.x = a.x > 0.f ? a.x : SLOPE * a.x;
            a.y = a.y > 0.f ? a.y : SLOPE * a.y;
            a.z = a.z > 0.f ? a.z : SLOPE * a.z;
            a.w = a.w > 0.f ? a.w : SLOPE * a.w;
            union { __half2 h2; unsigned u; } pa, pb;
            pa.h2 = __float22half2_rn(make_float2(a.x, a.y));
            pb.h2 = __float22half2_rn(make_float2(a.z, a.w));
            ((uint2*)xn)[(size_t)node * 32 + cl] = make_uint2(pa.u, pb.u);
        }
    }
}

// ---------------- dense head: out = (x@wd + bd) @ wo + bo ; xin fp16 ----------------
__global__ __launch_bounds__(256) void dense_gemm(
    const __half* __restrict__ xin, const float* __restrict__ wd, const float* __restrict__ bd,
    const float* __restrict__ wo, const float* __restrict__ bo, float* __restrict__ out, int n)
{
    __shared__ float xr[32 * ZSTR];
    int i0 = blockIdx.x * 32;
    int t = threadIdx.x;
    for (int p = t; p < 32 * 32; p += 256) {
        int r = p >> 5, c4 = p & 31;
        float4 v = {0.f, 0.f, 0.f, 0.f};
        if (i0 + r < n) v = unpack_h4(((const uint2*)xin)[(size_t)(i0 + r) * 32 + c4]);
        *(float4*)&xr[r * ZSTR + c4 * 4] = v;
    }
    __syncthreads();

    int cl = t & 63;
    int w = t >> 6;
    float4 acc[8] = {};
    const float4* wd4 = (const float4*)wd;
    float4 w0 = wd4[0 * 64 + cl], w1 = wd4[1 * 64 + cl];
    float4 w2 = wd4[2 * 64 + cl], w3 = wd4[3 * 64 + cl];
    for (int k = 0; k < C; k += 4) {
        int kn = (k + 4) & 127;
        float4 nw0 = wd4[(kn + 0) * 64 + cl];
        float4 nw1 = wd4[(kn + 1) * 64 + cl];
        float4 nw2 = wd4[(kn + 2) * 64 + cl];
        float4 nw3 = wd4[(kn + 3) * 64 + cl];
        #pragma unroll
        for (int nj = 0; nj < 8; ++nj) {
            float4 xv = *(const float4*)&xr[(w * 8 + nj) * ZSTR + k];
            acc[nj].x += xv.x * w0.x + xv.y * w1.x + xv.z * w2.x + xv.w * w3.x;
            acc[nj].y += xv.x * w0.y + xv.y * w1.y + xv.z * w2.y + xv.w * w3.y;
            acc[nj].z += xv.x * w0.z + xv.y * w1.z + xv.z * w2.z + xv.w * w3.z;
            acc[nj].w += xv.x * w0.w + xv.y * w1.w + xv.z * w2.w + xv.w * w3.w;
        }
        w0 = nw0; w1 = nw1; w2 = nw2; w3 = nw3;
    }
    float4 bdv = ((const float4*)bd)[cl];
    const float4* wo4 = (const float4*)wo;
    float4 woa = wo4[cl * 2 + 0];
    float4 wob = wo4[cl * 2 + 1];
    float bo0 = bo[0], bo1 = bo[1];
    #pragma unroll
    for (int nj = 0; nj < 8; ++nj) {
        float4 hid;
        hid.x = acc[nj].x + bdv.x;
        hid.y = acc[nj].y + bdv.y;
        hid.z = acc[nj].z + bdv.z;
        hid.w = acc[nj].w + bdv.w;
        float p0 = hid.x * woa.x + hid.y * woa.z + hid.z * wob.x + hid.w * wob.z;
        float p1 = hid.x * woa.y + hid.y * woa.w + hid.z * wob.y + hid.w * wob.w;
        #pragma unroll
        for (int off = 32; off; off >>= 1) {
            p0 += __shfl_down(p0, off);
            p1 += __shfl_down(p1, off);
        }
        int node = i0 + w * 8 + nj;
        if (cl == 0 && node < n) {
            out[(size_t)node * NOUT + 0] = bo0 + p0;
            out[(size_t)node * NOUT + 1] = bo1 + p1;
        }
    }
}

extern "C" void kernel_launch(void* const* d_in, const int* in_sizes, int n_in,
                              void* d_out, int out_size, void* d_ws, size_t ws_size,
                              hipStream_t stream) {
    const float* x0    = (const float*)d_in[0];
    const int*   ei    = (const int*)d_in[1];
    const float* convW = (const float*)d_in[2];
    const float* wd    = (const float*)d_in[3];
    const float* bd    = (const float*)d_in[4];
    const float* wo    = (const float*)d_in[5];
    const float* bo    = (const float*)d_in[6];
    float* out = (float*)d_out;

    int N = in_sizes[0] / C;
    int E = in_sizes[1] / 2;
    int L = in_sizes[2] / (C * C);
    const int* row = ei;
    const int* col = ei + E;
    int NB = (N + 1023) / 1024;

    char* p = (char*)d_ws;
    auto alloc = [&](size_t bytes) {
        char* r = p;
        p += (bytes + 255) & ~(size_t)255;
        return r;
    };
    int*    cnt    = (int*)alloc((size_t)N * 4);
    int*    offs   = (int*)alloc((size_t)(N + 1) * 4);
    int*    cursor = (int*)alloc((size_t)N * 4);
    int*    bsum   = (int*)alloc((size_t)NB * 4);
    int*    bbase  = (int*)alloc((size_t)NB * 4);
    int2*   csr    = (int2*)alloc((size_t)E * 8);
    float*  dinv   = (float*)alloc((size_t)N * 4);
    __half* x0h    = (__half*)alloc((size_t)N * C * 2);
    __half* bufA   = (__half*)alloc((size_t)N * C * 2);
    __half* bufB   = (__half*)alloc((size_t)N * C * 2);

    hipMemsetAsync(cnt, 0, (size_t)N * 4, stream);
    count_kernel<<<(E + 255) / 256, 256, 0, stream>>>(col, cnt, E);
    scanA_kernel<<<NB, 1024, 0, stream>>>(cnt, offs, bsum, dinv, N);
    scanB_kernel<<<1, 1024, 0, stream>>>(bsum, bbase, NB);
    scanC_kernel<<<(N + 256) / 256, 256, 0, stream>>>(offs, cursor, bbase, N, E);
    fill_kernel<<<(E + 255) / 256, 256, 0, stream>>>(row, col, dinv, cursor, csr, E);
    convert_kernel<<<(N * 32 + 255) / 256, 256, 0, stream>>>(x0, x0h, N);

    const __half* xc = x0h;
    for (int l = 0; l < L; ++l) {
        __half* hbuf = (l & 1) ? bufB : bufA;
        agg_kernel<<<(N + 3) / 4, 256, 0, stream>>>(xc, offs, csr, dinv, hbuf, N);
        layer_gemm<<<(N + 63) / 64, 256, 0, stream>>>(hbuf, x0h,
                                                      convW + (size_t)l * C * C, hbuf, N);
        xc = hbuf;
    }
    dense_gemm<<<(N + 31) / 32, 256, 0, stream>>>(xc, wd, bd, wo, bo, out, N);
}